// Round 1
// baseline (745.369 us; speedup 1.0000x reference)
//
#include <hip/hip_runtime.h>
#include <hip/hip_bf16.h>
#include <math.h>

#define TT 4096   // tokens (B*S)
#define HH 1024   // hidden
#define EE 8      // experts
#define II 1024   // intermediate

typedef __bf16 bf16x8 __attribute__((ext_vector_type(8)));
typedef float  floatx4 __attribute__((ext_vector_type(4)));
typedef __hip_bfloat16 bf16;

// async global->LDS, 16B per lane. LDS dest is wave-uniform base + lane*16;
// global address is per-lane (gather allowed).
__device__ __forceinline__ void async_copy16(const void* g, void* s) {
  __builtin_amdgcn_global_load_lds((__attribute__((address_space(1))) void*)g,
                                   (__attribute__((address_space(3))) void*)s,
                                   16, 0, 0);
}

// ---------------- weight transpose+convert: [1024][1024] f32 -> [1024][1024]^T bf16, per expert ----------------
__global__ __launch_bounds__(256) void transpose_convert(const float* __restrict__ src,
                                                         bf16* __restrict__ dst) {
  __shared__ float tile[32][33];
  const int e = blockIdx.z;
  const float* s = src + (size_t)e * 1024 * 1024;
  bf16* d = dst + (size_t)e * 1024 * 1024;
  const int tx = threadIdx.x, ty = threadIdx.y;     // 32 x 8
  const int r0 = blockIdx.y * 32, c0 = blockIdx.x * 32;
  #pragma unroll
  for (int i = 0; i < 32; i += 8)
    tile[ty + i][tx] = s[(size_t)(r0 + ty + i) * 1024 + (c0 + tx)];
  __syncthreads();
  #pragma unroll
  for (int i = 0; i < 32; i += 8)
    d[(size_t)(c0 + ty + i) * 1024 + (r0 + tx)] = __float2bfloat16(tile[tx][ty + i]);
}

// ---------------- router: logits, top-2, scatter, aux stats, x->bf16 ----------------
__global__ __launch_bounds__(256) void router_kernel(
    const float* __restrict__ x, const float* __restrict__ Wr,
    bf16* __restrict__ xb, int* __restrict__ cnt, float* __restrict__ imp,
    int* __restrict__ tok_list, float* __restrict__ gate_ls)
{
  const int w = threadIdx.x >> 6, lane = threadIdx.x & 63;
  const int t = blockIdx.x * 4 + w;
  const float* xr = x + (size_t)t * HH;
  float acc[8] = {0.f,0.f,0.f,0.f,0.f,0.f,0.f,0.f};
  #pragma unroll
  for (int i = 0; i < 16; i++) {
    int h = lane + i * 64;
    float xv = xr[h];
    xb[(size_t)t * HH + h] = __float2bfloat16(xv);
    const float4* wr = (const float4*)(Wr + h * 8);
    float4 a = wr[0], b = wr[1];
    acc[0] += xv * a.x; acc[1] += xv * a.y; acc[2] += xv * a.z; acc[3] += xv * a.w;
    acc[4] += xv * b.x; acc[5] += xv * b.y; acc[6] += xv * b.z; acc[7] += xv * b.w;
  }
  #pragma unroll
  for (int e = 0; e < 8; e++) {
    #pragma unroll
    for (int off = 32; off > 0; off >>= 1)
      acc[e] += __shfl_xor(acc[e], off);
  }
  if (lane == 0) {
    int i0 = 0;
    #pragma unroll
    for (int e = 1; e < 8; e++) if (acc[e] > acc[i0]) i0 = e;   // lowest index wins ties, like lax.top_k
    int i1 = (i0 == 0) ? 1 : 0;
    #pragma unroll
    for (int e = 0; e < 8; e++) if (e != i0 && acc[e] > acc[i1]) i1 = e;
    float mx = acc[i0];
    float pe[8]; float s = 0.f;
    #pragma unroll
    for (int e = 0; e < 8; e++) { pe[e] = __expf(acc[e] - mx); s += pe[e]; }
    float inv = 1.f / s;
    #pragma unroll
    for (int e = 0; e < 8; e++) atomicAdd(imp + e, pe[e] * inv);
    float p0 = pe[i0] * inv, p1 = pe[i1] * inv;
    float wn2 = 1.f / (p0 + p1);
    int pos0 = atomicAdd(cnt + i0, 1);
    tok_list[i0 * TT + pos0] = t; gate_ls[i0 * TT + pos0] = p0 * wn2;
    int pos1 = atomicAdd(cnt + i1, 1);
    tok_list[i1 * TT + pos1] = t; gate_ls[i1 * TT + pos1] = p1 * wn2;
  }
}

// ---------------- finalize: prefix offsets + aux loss ----------------
__global__ void finalize_kernel(const int* __restrict__ cnt, const float* __restrict__ imp,
                                int* __restrict__ offs, float* __restrict__ aux_out)
{
  if (threadIdx.x == 0 && blockIdx.x == 0) {
    int o = 0; float s = 0.f;
    for (int e = 0; e < 8; e++) { offs[e] = o; o += cnt[e]; s += (float)cnt[e] * imp[e]; }
    aux_out[0] = (float)EE * 0.01f * s / ((float)TT * (float)TT);
  }
}

// ---------------- gemm1: inter = silu(A@Wg) * (A@Wu), A gathered tokens ----------------
__global__ __launch_bounds__(256) void gemm1_kernel(
    const bf16* __restrict__ xb, const bf16* __restrict__ wg, const bf16* __restrict__ wu,
    const int* __restrict__ cnt, const int* __restrict__ offs,
    const int* __restrict__ tok_list, bf16* __restrict__ inter)
{
  const int e = blockIdx.z;
  const int M = cnt[e];
  const int m0 = blockIdx.y * 128;
  if (m0 >= M) return;
  const int n0 = blockIdx.x * 128;
  const int off = offs[e];

  __shared__ alignas(16) bf16 As[128 * 32];
  __shared__ alignas(16) bf16 Bg[128 * 32];
  __shared__ alignas(16) bf16 Bu[128 * 32];
  __shared__ int sTok[128];

  const int tid = threadIdx.x;
  if (tid < 128) {
    int p = m0 + tid;
    sTok[tid] = tok_list[e * TT + (p < M ? p : M - 1)];
  }

  const int w = tid >> 6, lane = tid & 63;
  const int lrow = lane >> 2, lch = (lane & 3) * 8;
  const int quad = lane >> 4, l16 = lane & 15;
  const int wm = (w >> 1) * 64, wn = (w & 1) * 64;

  const bf16* bgp = wg + ((size_t)e * II + n0) * HH;  // [n][k] rows
  const bf16* bup = wu + ((size_t)e * II + n0) * HH;

  floatx4 zero4 = {0.f, 0.f, 0.f, 0.f};
  floatx4 accg[4][4], accu[4][4];
  #pragma unroll
  for (int mi = 0; mi < 4; mi++)
    #pragma unroll
    for (int ni = 0; ni < 4; ni++) { accg[mi][ni] = zero4; accu[mi][ni] = zero4; }

  __syncthreads();  // sTok visible

  for (int k0 = 0; k0 < HH; k0 += 32) {
    if (k0) __syncthreads();                 // prior compute done before LDS overwrite
    #pragma unroll
    for (int i = 0; i < 6; i++) {            // 24 issues across 4 waves
      int issue = w + 4 * i;
      int q = issue & 7;
      int r = q * 16 + lrow;
      if (issue < 8) {
        int tok = sTok[r];
        async_copy16(xb + (size_t)tok * HH + k0 + lch, As + q * 512);
      } else if (issue < 16) {
        async_copy16(bgp + (size_t)r * HH + k0 + lch, Bg + q * 512);
      } else {
        async_copy16(bup + (size_t)r * HH + k0 + lch, Bu + q * 512);
      }
    }
    __syncthreads();                         // vmcnt drained by barrier semantics

    bf16x8 af[4], bgf[4], buf2[4];
    #pragma unroll
    for (int mi = 0; mi < 4; mi++)
      af[mi] = *(const bf16x8*)(As + (wm + mi * 16 + l16) * 32 + quad * 8);
    #pragma unroll
    for (int ni = 0; ni < 4; ni++) {
      bgf[ni]  = *(const bf16x8*)(Bg + (wn + ni * 16 + l16) * 32 + quad * 8);
      buf2[ni] = *(const bf16x8*)(Bu + (wn + ni * 16 + l16) * 32 + quad * 8);
    }
    #pragma unroll
    for (int mi = 0; mi < 4; mi++)
      #pragma unroll
      for (int ni = 0; ni < 4; ni++) {
        accg[mi][ni] = __builtin_amdgcn_mfma_f32_16x16x32_bf16(af[mi], bgf[ni],  accg[mi][ni], 0, 0, 0);
        accu[mi][ni] = __builtin_amdgcn_mfma_f32_16x16x32_bf16(af[mi], buf2[ni], accu[mi][ni], 0, 0, 0);
      }
  }

  // epilogue: silu(g)*u -> bf16 inter (compact slots), C/D: row=quad*4+reg, col=lane&15
  #pragma unroll
  for (int mi = 0; mi < 4; mi++)
    #pragma unroll
    for (int ni = 0; ni < 4; ni++) {
      #pragma unroll
      for (int r = 0; r < 4; r++) {
        int row = wm + mi * 16 + quad * 4 + r;
        int p = m0 + row;
        if (p < M) {
          float gv = accg[mi][ni][r], uv = accu[mi][ni][r];
          float val = gv / (1.f + __expf(-gv)) * uv;
          inter[(size_t)(off + p) * II + (n0 + wn + ni * 16 + l16)] = __float2bfloat16(val);
        }
      }
    }
}

// ---------------- gemm2: out += gate * (inter @ Wd^T) via atomicAdd ----------------
__global__ __launch_bounds__(256) void gemm2_kernel(
    const bf16* __restrict__ inter, const bf16* __restrict__ wd,
    const int* __restrict__ cnt, const int* __restrict__ offs,
    const int* __restrict__ tok_list, const float* __restrict__ gate_ls,
    float* __restrict__ out)
{
  const int e = blockIdx.z;
  const int M = cnt[e];
  const int m0 = blockIdx.y * 128;
  if (m0 >= M) return;
  const int n0 = blockIdx.x * 128;
  const int off = offs[e];

  __shared__ alignas(16) bf16 As[128 * 32];
  __shared__ alignas(16) bf16 Bs[128 * 32];
  __shared__ int sTok[128];
  __shared__ float sGw[128];

  const int tid = threadIdx.x;
  if (tid < 128) {
    int p = m0 + tid;
    int pc = p < M ? p : M - 1;
    sTok[tid] = tok_list[e * TT + pc];
    sGw[tid]  = gate_ls[e * TT + pc];
  }
  const int w = tid >> 6, lane = tid & 63;
  const int lrow = lane >> 2, lch = (lane & 3) * 8;
  const int quad = lane >> 4, l16 = lane & 15;
  const int wm = (w >> 1) * 64, wn = (w & 1) * 64;
  const bf16* bp = wd + ((size_t)e * HH + n0) * II;   // [n=h][k=i] rows

  floatx4 zero4 = {0.f, 0.f, 0.f, 0.f};
  floatx4 acc[4][4];
  #pragma unroll
  for (int mi = 0; mi < 4; mi++)
    #pragma unroll
    for (int ni = 0; ni < 4; ni++) acc[mi][ni] = zero4;

  __syncthreads();

  for (int k0 = 0; k0 < II; k0 += 32) {
    if (k0) __syncthreads();
    #pragma unroll
    for (int i = 0; i < 4; i++) {            // 16 issues across 4 waves
      int issue = w + 4 * i;
      int q = issue & 7;
      int r = q * 16 + lrow;
      if (issue < 8) {
        int p = m0 + r; int pc = p < M ? p : M - 1;
        async_copy16(inter + (size_t)(off + pc) * II + k0 + lch, As + q * 512);
      } else {
        async_copy16(bp + (size_t)r * II + k0 + lch, Bs + q * 512);
      }
    }
    __syncthreads();

    bf16x8 af[4], bf_[4];
    #pragma unroll
    for (int mi = 0; mi < 4; mi++)
      af[mi] = *(const bf16x8*)(As + (wm + mi * 16 + l16) * 32 + quad * 8);
    #pragma unroll
    for (int ni = 0; ni < 4; ni++)
      bf_[ni] = *(const bf16x8*)(Bs + (wn + ni * 16 + l16) * 32 + quad * 8);
    #pragma unroll
    for (int mi = 0; mi < 4; mi++)
      #pragma unroll
      for (int ni = 0; ni < 4; ni++)
        acc[mi][ni] = __builtin_amdgcn_mfma_f32_16x16x32_bf16(af[mi], bf_[ni], acc[mi][ni], 0, 0, 0);
  }

  #pragma unroll
  for (int mi = 0; mi < 4; mi++)
    #pragma unroll
    for (int ni = 0; ni < 4; ni++) {
      #pragma unroll
      for (int r = 0; r < 4; r++) {
        int row = wm + mi * 16 + quad * 4 + r;
        int p = m0 + row;
        if (p < M) {
          float val = acc[mi][ni][r] * sGw[row];
          atomicAdd(out + (size_t)sTok[row] * HH + (n0 + wn + ni * 16 + l16), val);
        }
      }
    }
}

// ---------------- host ----------------
extern "C" void kernel_launch(void* const* d_in, const int* in_sizes, int n_in,
                              void* d_out, int out_size, void* d_ws, size_t ws_size,
                              hipStream_t stream)
{
  const float* x  = (const float*)d_in[0];
  const float* Wr = (const float*)d_in[1];
  const float* Wg = (const float*)d_in[2];
  const float* Wu = (const float*)d_in[3];
  const float* Wd = (const float*)d_in[4];
  float* out = (float*)d_out;
  char* ws = (char*)d_ws;

  // workspace layout (bytes): total ~75.8 MB
  int*   cnt      = (int*)(ws + 0);          // 8 ints
  float* imp      = (float*)(ws + 64);       // 8 floats
  int*   offs     = (int*)(ws + 128);        // 8 ints
  int*   tok_list = (int*)(ws + 1024);       // E*T ints   (128 KB)
  float* gate_ls  = (float*)(ws + 132096);   // E*T floats (128 KB)
  bf16*  xb       = (bf16*)(ws + 263168);    // T*H bf16   (8 MB)
  bf16*  wgb      = (bf16*)(ws + 8651776);   // E*I*H bf16 (16 MB, transposed [e][i][h])
  bf16*  wub      = (bf16*)(ws + 25428992);  // 16 MB
  bf16*  wdb      = (bf16*)(ws + 42206208);  // 16 MB, transposed [e][h][i]
  bf16*  inter    = (bf16*)(ws + 58983424);  // 2T*I bf16  (16 MB, compact slots)

  hipMemsetAsync(ws, 0, 1024, stream);                                  // cnt/imp
  hipMemsetAsync(d_out, 0, (size_t)out_size * sizeof(float), stream);   // atomic accum base

  dim3 tb(32, 8);
  dim3 tg(32, 32, 8);
  transpose_convert<<<tg, tb, 0, stream>>>(Wg, wgb);
  transpose_convert<<<tg, tb, 0, stream>>>(Wu, wub);
  transpose_convert<<<tg, tb, 0, stream>>>(Wd, wdb);
  router_kernel<<<1024, 256, 0, stream>>>(x, Wr, xb, cnt, imp, tok_list, gate_ls);
  finalize_kernel<<<1, 64, 0, stream>>>(cnt, imp, offs, out + (size_t)TT * HH);
  gemm1_kernel<<<dim3(8, 32, 8), 256, 0, stream>>>(xb, wgb, wub, cnt, offs, tok_list, inter);
  gemm2_kernel<<<dim3(8, 32, 8), 256, 0, stream>>>(inter, wdb, cnt, offs, tok_list, gate_ls, out);
}

// Round 2
// 340.840 us; speedup vs baseline: 2.1869x; 2.1869x over previous
//
#include <hip/hip_runtime.h>
#include <hip/hip_bf16.h>
#include <math.h>

#define TT 4096   // tokens (B*S)
#define HH 1024   // hidden
#define EE 8      // experts
#define II 1024   // intermediate

typedef __bf16 bf16x8 __attribute__((ext_vector_type(8)));
typedef float  floatx4 __attribute__((ext_vector_type(4)));
typedef __hip_bfloat16 bf16;

// async global->LDS, 16B per lane. LDS dest is wave-uniform base + lane*16;
// global address is per-lane (gather allowed).
__device__ __forceinline__ void async_copy16(const void* g, void* s) {
  __builtin_amdgcn_global_load_lds((__attribute__((address_space(1))) void*)g,
                                   (__attribute__((address_space(3))) void*)s,
                                   16, 0, 0);
}

// ---------------- weight transpose+convert: [1024][1024] f32 -> [1024][1024]^T bf16, per expert ----------------
__global__ __launch_bounds__(256) void transpose_convert(const float* __restrict__ src,
                                                         bf16* __restrict__ dst) {
  __shared__ float tile[32][33];
  const int e = blockIdx.z;
  const float* s = src + (size_t)e * 1024 * 1024;
  bf16* d = dst + (size_t)e * 1024 * 1024;
  const int tx = threadIdx.x, ty = threadIdx.y;     // 32 x 8
  const int r0 = blockIdx.y * 32, c0 = blockIdx.x * 32;
  #pragma unroll
  for (int i = 0; i < 32; i += 8)
    tile[ty + i][tx] = s[(size_t)(r0 + ty + i) * 1024 + (c0 + tx)];
  __syncthreads();
  #pragma unroll
  for (int i = 0; i < 32; i += 8)
    d[(size_t)(c0 + ty + i) * 1024 + (r0 + tx)] = __float2bfloat16(tile[tx][ty + i]);
}

// ---------------- router: logits, top-2 -> per-token records; per-block imp partials; x->bf16 ----------------
// NO global atomics (R1 post-mortem: 40960 same-cacheline RMWs cost 425 us).
__global__ __launch_bounds__(256) void router_kernel(
    const float* __restrict__ x, const float* __restrict__ Wr,
    bf16* __restrict__ xb, int* __restrict__ pair, float2* __restrict__ w2,
    float* __restrict__ impPart)
{
  __shared__ float simp[8];
  const int tid = threadIdx.x;
  if (tid < 8) simp[tid] = 0.f;
  __syncthreads();

  const int w = tid >> 6, lane = tid & 63;
  const int t = blockIdx.x * 4 + w;
  const float* xr = x + (size_t)t * HH;
  float acc[8] = {0.f,0.f,0.f,0.f,0.f,0.f,0.f,0.f};
  #pragma unroll
  for (int i = 0; i < 16; i++) {
    int h = lane + i * 64;
    float xv = xr[h];
    xb[(size_t)t * HH + h] = __float2bfloat16(xv);
    const float4* wr = (const float4*)(Wr + h * 8);
    float4 a = wr[0], b = wr[1];
    acc[0] += xv * a.x; acc[1] += xv * a.y; acc[2] += xv * a.z; acc[3] += xv * a.w;
    acc[4] += xv * b.x; acc[5] += xv * b.y; acc[6] += xv * b.z; acc[7] += xv * b.w;
  }
  #pragma unroll
  for (int e = 0; e < 8; e++) {
    #pragma unroll
    for (int off = 32; off > 0; off >>= 1)
      acc[e] += __shfl_xor(acc[e], off);
  }
  if (lane == 0) {
    int i0 = 0;
    #pragma unroll
    for (int e = 1; e < 8; e++) if (acc[e] > acc[i0]) i0 = e;   // lowest index wins ties, like lax.top_k
    int i1 = (i0 == 0) ? 1 : 0;
    #pragma unroll
    for (int e = 0; e < 8; e++) if (e != i0 && acc[e] > acc[i1]) i1 = e;
    float mx = acc[i0];
    float pe[8]; float s = 0.f;
    #pragma unroll
    for (int e = 0; e < 8; e++) { pe[e] = __expf(acc[e] - mx); s += pe[e]; }
    float inv = 1.f / s;
    #pragma unroll
    for (int e = 0; e < 8; e++) atomicAdd(simp + e, pe[e] * inv);   // LDS atomic: cheap
    float p0 = pe[i0] * inv, p1 = pe[i1] * inv;
    float wn2 = 1.f / (p0 + p1);
    pair[t] = i0 | (i1 << 8);
    w2[t] = make_float2(p0 * wn2, p1 * wn2);
  }
  __syncthreads();
  if (tid < 8) impPart[blockIdx.x * 8 + tid] = simp[tid];
}

// ---------------- scatter: per-block LDS histogram -> 8 global atomics/block ----------------
__global__ __launch_bounds__(256) void scatter_kernel(
    const int* __restrict__ pair, const float2* __restrict__ w2,
    int* __restrict__ cnt, int* __restrict__ tok_list, float* __restrict__ gate_ls)
{
  __shared__ int lcnt[8];
  __shared__ int lbase[8];
  const int tid = threadIdx.x;
  const int t = blockIdx.x * 256 + tid;
  if (tid < 8) lcnt[tid] = 0;
  __syncthreads();
  int pr = pair[t];
  float2 ww = w2[t];
  int e0 = pr & 0xff, e1 = pr >> 8;
  int lp0 = atomicAdd(lcnt + e0, 1);
  int lp1 = atomicAdd(lcnt + e1, 1);
  __syncthreads();
  if (tid < 8) lbase[tid] = atomicAdd(cnt + tid, lcnt[tid]);   // 8 global atomics per block
  __syncthreads();
  int p0 = lbase[e0] + lp0, p1 = lbase[e1] + lp1;
  tok_list[e0 * TT + p0] = t; gate_ls[e0 * TT + p0] = ww.x;
  tok_list[e1 * TT + p1] = t; gate_ls[e1 * TT + p1] = ww.y;
}

// ---------------- finalize: reduce imp partials, prefix offsets, aux loss ----------------
__global__ __launch_bounds__(256) void finalize_kernel(
    const int* __restrict__ cnt, const float* __restrict__ impPart,
    int* __restrict__ offs, float* __restrict__ aux_out)
{
  __shared__ float part[256];
  __shared__ float impf[8];
  const int tid = threadIdx.x;
  const int e = tid & 7, r = tid >> 3;          // 32 chunks x 8 experts
  float s = 0.f;
  for (int i = r; i < 1024; i += 32) s += impPart[i * 8 + e];
  part[tid] = s;
  __syncthreads();
  if (tid < 8) {
    float ss = 0.f;
    #pragma unroll
    for (int j = 0; j < 32; j++) ss += part[j * 8 + tid];
    impf[tid] = ss;
  }
  __syncthreads();
  if (tid == 0) {
    int o = 0; float sl = 0.f;
    for (int e2 = 0; e2 < 8; e2++) { offs[e2] = o; o += cnt[e2]; sl += (float)cnt[e2] * impf[e2]; }
    aux_out[0] = (float)EE * 0.01f * sl / ((float)TT * (float)TT);
  }
}

// ---------------- gemm1: inter = silu(A@Wg) * (A@Wu), A gathered tokens ----------------
__global__ __launch_bounds__(256) void gemm1_kernel(
    const bf16* __restrict__ xb, const bf16* __restrict__ wg, const bf16* __restrict__ wu,
    const int* __restrict__ cnt, const int* __restrict__ offs,
    const int* __restrict__ tok_list, bf16* __restrict__ inter)
{
  const int e = blockIdx.z;
  const int M = cnt[e];
  const int m0 = blockIdx.y * 128;
  if (m0 >= M) return;
  const int n0 = blockIdx.x * 128;
  const int off = offs[e];

  __shared__ alignas(16) bf16 As[128 * 32];
  __shared__ alignas(16) bf16 Bg[128 * 32];
  __shared__ alignas(16) bf16 Bu[128 * 32];
  __shared__ int sTok[128];

  const int tid = threadIdx.x;
  if (tid < 128) {
    int p = m0 + tid;
    sTok[tid] = tok_list[e * TT + (p < M ? p : M - 1)];
  }

  const int w = tid >> 6, lane = tid & 63;
  const int lrow = lane >> 2, lch = (lane & 3) * 8;
  const int quad = lane >> 4, l16 = lane & 15;
  const int wm = (w >> 1) * 64, wn = (w & 1) * 64;

  const bf16* bgp = wg + ((size_t)e * II + n0) * HH;  // [n][k] rows
  const bf16* bup = wu + ((size_t)e * II + n0) * HH;

  floatx4 zero4 = {0.f, 0.f, 0.f, 0.f};
  floatx4 accg[4][4], accu[4][4];
  #pragma unroll
  for (int mi = 0; mi < 4; mi++)
    #pragma unroll
    for (int ni = 0; ni < 4; ni++) { accg[mi][ni] = zero4; accu[mi][ni] = zero4; }

  __syncthreads();  // sTok visible

  for (int k0 = 0; k0 < HH; k0 += 32) {
    if (k0) __syncthreads();                 // prior compute done before LDS overwrite
    #pragma unroll
    for (int i = 0; i < 6; i++) {            // 24 issues across 4 waves
      int issue = w + 4 * i;
      int q = issue & 7;
      int r = q * 16 + lrow;
      if (issue < 8) {
        int tok = sTok[r];
        async_copy16(xb + (size_t)tok * HH + k0 + lch, As + q * 512);
      } else if (issue < 16) {
        async_copy16(bgp + (size_t)r * HH + k0 + lch, Bg + q * 512);
      } else {
        async_copy16(bup + (size_t)r * HH + k0 + lch, Bu + q * 512);
      }
    }
    __syncthreads();                         // vmcnt drained by barrier semantics

    bf16x8 af[4], bgf[4], buf2[4];
    #pragma unroll
    for (int mi = 0; mi < 4; mi++)
      af[mi] = *(const bf16x8*)(As + (wm + mi * 16 + l16) * 32 + quad * 8);
    #pragma unroll
    for (int ni = 0; ni < 4; ni++) {
      bgf[ni]  = *(const bf16x8*)(Bg + (wn + ni * 16 + l16) * 32 + quad * 8);
      buf2[ni] = *(const bf16x8*)(Bu + (wn + ni * 16 + l16) * 32 + quad * 8);
    }
    #pragma unroll
    for (int mi = 0; mi < 4; mi++)
      #pragma unroll
      for (int ni = 0; ni < 4; ni++) {
        accg[mi][ni] = __builtin_amdgcn_mfma_f32_16x16x32_bf16(af[mi], bgf[ni],  accg[mi][ni], 0, 0, 0);
        accu[mi][ni] = __builtin_amdgcn_mfma_f32_16x16x32_bf16(af[mi], buf2[ni], accu[mi][ni], 0, 0, 0);
      }
  }

  // epilogue: silu(g)*u -> bf16 inter (compact slots), C/D: row=quad*4+reg, col=lane&15
  #pragma unroll
  for (int mi = 0; mi < 4; mi++)
    #pragma unroll
    for (int ni = 0; ni < 4; ni++) {
      #pragma unroll
      for (int r = 0; r < 4; r++) {
        int row = wm + mi * 16 + quad * 4 + r;
        int p = m0 + row;
        if (p < M) {
          float gv = accg[mi][ni][r], uv = accu[mi][ni][r];
          float val = gv / (1.f + __expf(-gv)) * uv;
          inter[(size_t)(off + p) * II + (n0 + wn + ni * 16 + l16)] = __float2bfloat16(val);
        }
      }
    }
}

// ---------------- gemm2: out += gate * (inter @ Wd^T) via atomicAdd ----------------
__global__ __launch_bounds__(256) void gemm2_kernel(
    const bf16* __restrict__ inter, const bf16* __restrict__ wd,
    const int* __restrict__ cnt, const int* __restrict__ offs,
    const int* __restrict__ tok_list, const float* __restrict__ gate_ls,
    float* __restrict__ out)
{
  const int e = blockIdx.z;
  const int M = cnt[e];
  const int m0 = blockIdx.y * 128;
  if (m0 >= M) return;
  const int n0 = blockIdx.x * 128;
  const int off = offs[e];

  __shared__ alignas(16) bf16 As[128 * 32];
  __shared__ alignas(16) bf16 Bs[128 * 32];
  __shared__ int sTok[128];
  __shared__ float sGw[128];

  const int tid = threadIdx.x;
  if (tid < 128) {
    int p = m0 + tid;
    int pc = p < M ? p : M - 1;
    sTok[tid] = tok_list[e * TT + pc];
    sGw[tid]  = gate_ls[e * TT + pc];
  }
  const int w = tid >> 6, lane = tid & 63;
  const int lrow = lane >> 2, lch = (lane & 3) * 8;
  const int quad = lane >> 4, l16 = lane & 15;
  const int wm = (w >> 1) * 64, wn = (w & 1) * 64;
  const bf16* bp = wd + ((size_t)e * HH + n0) * II;   // [n=h][k=i] rows

  floatx4 zero4 = {0.f, 0.f, 0.f, 0.f};
  floatx4 acc[4][4];
  #pragma unroll
  for (int mi = 0; mi < 4; mi++)
    #pragma unroll
    for (int ni = 0; ni < 4; ni++) acc[mi][ni] = zero4;

  __syncthreads();

  for (int k0 = 0; k0 < II; k0 += 32) {
    if (k0) __syncthreads();
    #pragma unroll
    for (int i = 0; i < 4; i++) {            // 16 issues across 4 waves
      int issue = w + 4 * i;
      int q = issue & 7;
      int r = q * 16 + lrow;
      if (issue < 8) {
        int p = m0 + r; int pc = p < M ? p : M - 1;
        async_copy16(inter + (size_t)(off + pc) * II + k0 + lch, As + q * 512);
      } else {
        async_copy16(bp + (size_t)r * II + k0 + lch, Bs + q * 512);
      }
    }
    __syncthreads();

    bf16x8 af[4], bf_[4];
    #pragma unroll
    for (int mi = 0; mi < 4; mi++)
      af[mi] = *(const bf16x8*)(As + (wm + mi * 16 + l16) * 32 + quad * 8);
    #pragma unroll
    for (int ni = 0; ni < 4; ni++)
      bf_[ni] = *(const bf16x8*)(Bs + (wn + ni * 16 + l16) * 32 + quad * 8);
    #pragma unroll
    for (int mi = 0; mi < 4; mi++)
      #pragma unroll
      for (int ni = 0; ni < 4; ni++)
        acc[mi][ni] = __builtin_amdgcn_mfma_f32_16x16x32_bf16(af[mi], bf_[ni], acc[mi][ni], 0, 0, 0);
  }

  #pragma unroll
  for (int mi = 0; mi < 4; mi++)
    #pragma unroll
    for (int ni = 0; ni < 4; ni++) {
      #pragma unroll
      for (int r = 0; r < 4; r++) {
        int row = wm + mi * 16 + quad * 4 + r;
        int p = m0 + row;
        if (p < M) {
          float val = acc[mi][ni][r] * sGw[row];
          atomicAdd(out + (size_t)sTok[row] * HH + (n0 + wn + ni * 16 + l16), val);
        }
      }
    }
}

// ---------------- host ----------------
extern "C" void kernel_launch(void* const* d_in, const int* in_sizes, int n_in,
                              void* d_out, int out_size, void* d_ws, size_t ws_size,
                              hipStream_t stream)
{
  const float* x  = (const float*)d_in[0];
  const float* Wr = (const float*)d_in[1];
  const float* Wg = (const float*)d_in[2];
  const float* Wu = (const float*)d_in[3];
  const float* Wd = (const float*)d_in[4];
  float* out = (float*)d_out;
  char* ws = (char*)d_ws;

  // workspace layout (bytes): total ~75.9 MB
  int*    cnt      = (int*)(ws + 0);          // 8 ints (zeroed)
  int*    offs     = (int*)(ws + 256);        // 8 ints
  float*  impPart  = (float*)(ws + 512);      // 1024*8 floats (32 KB)
  int*    pair     = (int*)(ws + 33280);      // T ints (16 KB)
  float2* w2       = (float2*)(ws + 49664);   // T float2 (32 KB)
  int*    tok_list = (int*)(ws + 98304);      // E*T ints   (128 KB)
  float*  gate_ls  = (float*)(ws + 229376);   // E*T floats (128 KB)
  bf16*   xb       = (bf16*)(ws + 360448);    // T*H bf16   (8 MB)
  bf16*   wgb      = (bf16*)(ws + 8749056);   // E*I*H bf16 (16 MB, transposed [e][i][h])
  bf16*   wub      = (bf16*)(ws + 25526272);  // 16 MB
  bf16*   wdb      = (bf16*)(ws + 42303488);  // 16 MB, transposed [e][h][i]
  bf16*   inter    = (bf16*)(ws + 59080704);  // 2T*I bf16  (16 MB, compact slots)

  hipMemsetAsync(ws, 0, 512, stream);                                   // cnt
  hipMemsetAsync(d_out, 0, (size_t)out_size * sizeof(float), stream);   // atomic accum base

  dim3 tb(32, 8);
  dim3 tg(32, 32, 8);
  transpose_convert<<<tg, tb, 0, stream>>>(Wg, wgb);
  transpose_convert<<<tg, tb, 0, stream>>>(Wu, wub);
  transpose_convert<<<tg, tb, 0, stream>>>(Wd, wdb);
  router_kernel<<<1024, 256, 0, stream>>>(x, Wr, xb, pair, w2, impPart);
  scatter_kernel<<<16, 256, 0, stream>>>(pair, w2, cnt, tok_list, gate_ls);
  finalize_kernel<<<1, 256, 0, stream>>>(cnt, impPart, offs, out + (size_t)TT * HH);
  gemm1_kernel<<<dim3(8, 32, 8), 256, 0, stream>>>(xb, wgb, wub, cnt, offs, tok_list, inter);
  gemm2_kernel<<<dim3(8, 32, 8), 256, 0, stream>>>(inter, wdb, cnt, offs, tok_list, gate_ls, out);
}

// Round 3
// 314.918 us; speedup vs baseline: 2.3669x; 1.0823x over previous
//
#include <hip/hip_runtime.h>
#include <hip/hip_bf16.h>
#include <math.h>

#define TT 4096   // tokens (B*S)
#define HH 1024   // hidden
#define EE 8      // experts
#define II 1024   // intermediate

typedef __bf16 bf16x8 __attribute__((ext_vector_type(8)));
typedef float  floatx4 __attribute__((ext_vector_type(4)));
typedef __hip_bfloat16 bf16;

// async global->LDS, 16B per lane. LDS dest is wave-uniform base + lane*16;
// global address is per-lane (gather allowed).
__device__ __forceinline__ void async_copy16(const void* g, void* s) {
  __builtin_amdgcn_global_load_lds((__attribute__((address_space(1))) void*)g,
                                   (__attribute__((address_space(3))) void*)s,
                                   16, 0, 0);
}

// XOR swizzle: logical 16B chunk j of row r lives at phys chunk j ^ ((r>>1)&3).
// Staging picks the global column per lane so reads are conflict-free (2-way max).

// ---------------- weight transpose+convert (all 3 weights in one launch) ----------------
__global__ __launch_bounds__(256) void transpose_convert3(
    const float* __restrict__ Wg, const float* __restrict__ Wu, const float* __restrict__ Wd,
    bf16* __restrict__ wgb, bf16* __restrict__ wub, bf16* __restrict__ wdb) {
  __shared__ float tile[32][33];
  const int zi = blockIdx.z >> 3, e = blockIdx.z & 7;
  const float* s = (zi == 0 ? Wg : zi == 1 ? Wu : Wd) + (size_t)e * 1024 * 1024;
  bf16* d = (zi == 0 ? wgb : zi == 1 ? wub : wdb) + (size_t)e * 1024 * 1024;
  const int tx = threadIdx.x, ty = threadIdx.y;     // 32 x 8
  const int r0 = blockIdx.y * 32, c0 = blockIdx.x * 32;
  #pragma unroll
  for (int i = 0; i < 32; i += 8)
    tile[ty + i][tx] = s[(size_t)(r0 + ty + i) * 1024 + (c0 + tx)];
  __syncthreads();
  #pragma unroll
  for (int i = 0; i < 32; i += 8)
    d[(size_t)(c0 + ty + i) * 1024 + (r0 + tx)] = __float2bfloat16(tile[tx][ty + i]);
}

// ---------------- router: logits, top-2 -> per-token records; per-block imp partials; x->bf16 ----------------
__global__ __launch_bounds__(256) void router_kernel(
    const float* __restrict__ x, const float* __restrict__ Wr,
    bf16* __restrict__ xb, int* __restrict__ pair, float2* __restrict__ w2,
    float* __restrict__ impPart)
{
  __shared__ float simp[8];
  const int tid = threadIdx.x;
  if (tid < 8) simp[tid] = 0.f;
  __syncthreads();

  const int w = tid >> 6, lane = tid & 63;
  const int t = blockIdx.x * 4 + w;
  const float* xr = x + (size_t)t * HH;
  float acc[8] = {0.f,0.f,0.f,0.f,0.f,0.f,0.f,0.f};
  #pragma unroll
  for (int i = 0; i < 16; i++) {
    int h = lane + i * 64;
    float xv = xr[h];
    xb[(size_t)t * HH + h] = __float2bfloat16(xv);
    const float4* wr = (const float4*)(Wr + h * 8);
    float4 a = wr[0], b = wr[1];
    acc[0] += xv * a.x; acc[1] += xv * a.y; acc[2] += xv * a.z; acc[3] += xv * a.w;
    acc[4] += xv * b.x; acc[5] += xv * b.y; acc[6] += xv * b.z; acc[7] += xv * b.w;
  }
  #pragma unroll
  for (int e = 0; e < 8; e++) {
    #pragma unroll
    for (int off = 32; off > 0; off >>= 1)
      acc[e] += __shfl_xor(acc[e], off);
  }
  if (lane == 0) {
    int i0 = 0;
    #pragma unroll
    for (int e = 1; e < 8; e++) if (acc[e] > acc[i0]) i0 = e;   // lowest index wins ties, like lax.top_k
    int i1 = (i0 == 0) ? 1 : 0;
    #pragma unroll
    for (int e = 0; e < 8; e++) if (e != i0 && acc[e] > acc[i1]) i1 = e;
    float mx = acc[i0];
    float pe[8]; float s = 0.f;
    #pragma unroll
    for (int e = 0; e < 8; e++) { pe[e] = __expf(acc[e] - mx); s += pe[e]; }
    float inv = 1.f / s;
    #pragma unroll
    for (int e = 0; e < 8; e++) atomicAdd(simp + e, pe[e] * inv);   // LDS atomic: cheap
    float p0 = pe[i0] * inv, p1 = pe[i1] * inv;
    float wn2 = 1.f / (p0 + p1);
    pair[t] = i0 | (i1 << 8);
    w2[t] = make_float2(p0 * wn2, p1 * wn2);
  }
  __syncthreads();
  if (tid < 8) impPart[blockIdx.x * 8 + tid] = simp[tid];
}

// ---------------- scatter: per-block LDS histogram -> 8 global atomics/block ----------------
__global__ __launch_bounds__(256) void scatter_kernel(
    const int* __restrict__ pair, const float2* __restrict__ w2,
    int* __restrict__ cnt, int* __restrict__ tok_list, float* __restrict__ gate_ls)
{
  __shared__ int lcnt[8];
  __shared__ int lbase[8];
  const int tid = threadIdx.x;
  const int t = blockIdx.x * 256 + tid;
  if (tid < 8) lcnt[tid] = 0;
  __syncthreads();
  int pr = pair[t];
  float2 ww = w2[t];
  int e0 = pr & 0xff, e1 = pr >> 8;
  int lp0 = atomicAdd(lcnt + e0, 1);
  int lp1 = atomicAdd(lcnt + e1, 1);
  __syncthreads();
  if (tid < 8) lbase[tid] = atomicAdd(cnt + tid, lcnt[tid]);   // 8 global atomics per block
  __syncthreads();
  int p0 = lbase[e0] + lp0, p1 = lbase[e1] + lp1;
  tok_list[e0 * TT + p0] = t; gate_ls[e0 * TT + p0] = ww.x;
  tok_list[e1 * TT + p1] = t; gate_ls[e1 * TT + p1] = ww.y;
}

// ---------------- finalize: reduce imp partials, prefix offsets, aux loss ----------------
__global__ __launch_bounds__(256) void finalize_kernel(
    const int* __restrict__ cnt, const float* __restrict__ impPart,
    int* __restrict__ offs, float* __restrict__ aux_out)
{
  __shared__ float part[256];
  __shared__ float impf[8];
  const int tid = threadIdx.x;
  const int e = tid & 7, r = tid >> 3;          // 32 chunks x 8 experts
  float s = 0.f;
  for (int i = r; i < 1024; i += 32) s += impPart[i * 8 + e];
  part[tid] = s;
  __syncthreads();
  if (tid < 8) {
    float ss = 0.f;
    #pragma unroll
    for (int j = 0; j < 32; j++) ss += part[j * 8 + tid];
    impf[tid] = ss;
  }
  __syncthreads();
  if (tid == 0) {
    int o = 0; float sl = 0.f;
    for (int e2 = 0; e2 < 8; e2++) { offs[e2] = o; o += cnt[e2]; sl += (float)cnt[e2] * impf[e2]; }
    aux_out[0] = (float)EE * 0.01f * sl / ((float)TT * (float)TT);
  }
}

// ---------------- gemm1: inter = silu(A@Wg) * (A@Wu); 64x128 tile, 4 waves of 32x64 ----------------
__global__ __launch_bounds__(256, 4) void gemm1_kernel(
    const bf16* __restrict__ xb, const bf16* __restrict__ wg, const bf16* __restrict__ wu,
    const int* __restrict__ cnt, const int* __restrict__ offs,
    const int* __restrict__ tok_list, bf16* __restrict__ inter)
{
  const int e = blockIdx.z;
  const int M = cnt[e];
  const int m0 = blockIdx.y * 64;
  if (m0 >= M) return;
  const int n0 = blockIdx.x * 128;
  const int off = offs[e];

  __shared__ alignas(16) bf16 As[64 * 32];    // 4 KB, 4 chunks
  __shared__ alignas(16) bf16 Bg[128 * 32];   // 8 KB, 8 chunks
  __shared__ alignas(16) bf16 Bu[128 * 32];
  __shared__ int sTok[64];

  const int tid = threadIdx.x;
  if (tid < 64) {
    int p = m0 + tid;
    sTok[tid] = tok_list[e * TT + (p < M ? p : M - 1)];
  }

  const int w = tid >> 6, lane = tid & 63;
  const int lrow = lane >> 2, c4 = lane & 3;
  const int quad = lane >> 4, l16 = lane & 15;
  const int wm = (w & 1) * 32, wn = (w >> 1) * 64;

  const bf16* bgp = wg + ((size_t)e * II + n0) * HH;  // [n][k] rows
  const bf16* bup = wu + ((size_t)e * II + n0) * HH;

  floatx4 zero4 = {0.f, 0.f, 0.f, 0.f};
  floatx4 accg[2][4], accu[2][4];
  #pragma unroll
  for (int mi = 0; mi < 2; mi++)
    #pragma unroll
    for (int ni = 0; ni < 4; ni++) { accg[mi][ni] = zero4; accu[mi][ni] = zero4; }

  __syncthreads();  // sTok visible

  // precompute k-invariant staging pointers (5 issues/wave: 4 A + 8 Bg + 8 Bu chunks total)
  const bf16* src[5]; bf16* dst[5];
  #pragma unroll
  for (int i = 0; i < 5; i++) {
    int idx = w + 4 * i;
    if (idx < 4) {
      int q = idx, r = q * 16 + lrow;
      int col = ((c4 ^ ((r >> 1) & 3)) << 3);
      src[i] = xb + (size_t)sTok[r] * HH + col;
      dst[i] = As + q * 512;
    } else if (idx < 12) {
      int q = idx - 4, r = q * 16 + lrow;
      int col = ((c4 ^ ((r >> 1) & 3)) << 3);
      src[i] = bgp + (size_t)r * HH + col;
      dst[i] = Bg + q * 512;
    } else {
      int q = idx - 12, r = q * 16 + lrow;
      int col = ((c4 ^ ((r >> 1) & 3)) << 3);
      src[i] = bup + (size_t)r * HH + col;
      dst[i] = Bu + q * 512;
    }
  }
  // precompute k-invariant LDS read offsets (swizzled)
  int offA[2], offB[4];
  #pragma unroll
  for (int mi = 0; mi < 2; mi++) {
    int r = wm + mi * 16 + l16;
    offA[mi] = r * 32 + ((quad ^ ((r >> 1) & 3)) << 3);
  }
  #pragma unroll
  for (int ni = 0; ni < 4; ni++) {
    int r = wn + ni * 16 + l16;
    offB[ni] = r * 32 + ((quad ^ ((r >> 1) & 3)) << 3);
  }

  for (int k0 = 0; k0 < HH; k0 += 32) {
    if (k0) __syncthreads();                 // prior compute done before LDS overwrite
    #pragma unroll
    for (int i = 0; i < 5; i++) { async_copy16(src[i], dst[i]); src[i] += 32; }
    __syncthreads();                         // vmcnt drained by barrier semantics

    bf16x8 af0 = *(const bf16x8*)(As + offA[0]);
    bf16x8 af1 = *(const bf16x8*)(As + offA[1]);
    #pragma unroll
    for (int ni = 0; ni < 4; ni++) {
      bf16x8 bg = *(const bf16x8*)(Bg + offB[ni]);
      bf16x8 bu = *(const bf16x8*)(Bu + offB[ni]);
      accg[0][ni] = __builtin_amdgcn_mfma_f32_16x16x32_bf16(af0, bg, accg[0][ni], 0, 0, 0);
      accg[1][ni] = __builtin_amdgcn_mfma_f32_16x16x32_bf16(af1, bg, accg[1][ni], 0, 0, 0);
      accu[0][ni] = __builtin_amdgcn_mfma_f32_16x16x32_bf16(af0, bu, accu[0][ni], 0, 0, 0);
      accu[1][ni] = __builtin_amdgcn_mfma_f32_16x16x32_bf16(af1, bu, accu[1][ni], 0, 0, 0);
    }
  }

  // epilogue: silu(g)*u -> bf16 inter (compact slots), C/D: row=quad*4+reg, col=lane&15
  #pragma unroll
  for (int mi = 0; mi < 2; mi++)
    #pragma unroll
    for (int ni = 0; ni < 4; ni++) {
      #pragma unroll
      for (int r = 0; r < 4; r++) {
        int row = wm + mi * 16 + quad * 4 + r;
        int p = m0 + row;
        if (p < M) {
          float gv = accg[mi][ni][r], uv = accu[mi][ni][r];
          float val = gv / (1.f + __expf(-gv)) * uv;
          inter[(size_t)(off + p) * II + (n0 + wn + ni * 16 + l16)] = __float2bfloat16(val);
        }
      }
    }
}

// ---------------- gemm2: out += gate * (inter @ Wd^T); 64x128 tile ----------------
__global__ __launch_bounds__(256, 4) void gemm2_kernel(
    const bf16* __restrict__ inter, const bf16* __restrict__ wd,
    const int* __restrict__ cnt, const int* __restrict__ offs,
    const int* __restrict__ tok_list, const float* __restrict__ gate_ls,
    float* __restrict__ out)
{
  const int e = blockIdx.z;
  const int M = cnt[e];
  const int m0 = blockIdx.y * 64;
  if (m0 >= M) return;
  const int n0 = blockIdx.x * 128;
  const int off = offs[e];

  __shared__ alignas(16) bf16 As[64 * 32];
  __shared__ alignas(16) bf16 Bs[128 * 32];
  __shared__ int sTok[64];
  __shared__ float sGw[64];

  const int tid = threadIdx.x;
  if (tid < 64) {
    int p = m0 + tid;
    int pc = p < M ? p : M - 1;
    sTok[tid] = tok_list[e * TT + pc];
    sGw[tid]  = gate_ls[e * TT + pc];
  }
  const int w = tid >> 6, lane = tid & 63;
  const int lrow = lane >> 2, c4 = lane & 3;
  const int quad = lane >> 4, l16 = lane & 15;
  const int wm = (w & 1) * 32, wn = (w >> 1) * 64;
  const bf16* bp = wd + ((size_t)e * HH + n0) * II;   // [n=h][k=i] rows

  floatx4 zero4 = {0.f, 0.f, 0.f, 0.f};
  floatx4 acc[2][4];
  #pragma unroll
  for (int mi = 0; mi < 2; mi++)
    #pragma unroll
    for (int ni = 0; ni < 4; ni++) acc[mi][ni] = zero4;

  __syncthreads();

  const bf16* src[3]; bf16* dst[3];
  #pragma unroll
  for (int i = 0; i < 3; i++) {
    int idx = w + 4 * i;
    if (idx < 4) {
      int q = idx, r = q * 16 + lrow;
      int col = ((c4 ^ ((r >> 1) & 3)) << 3);
      int p = m0 + r; int pc = p < M ? p : M - 1;
      src[i] = inter + (size_t)(off + pc) * II + col;
      dst[i] = As + q * 512;
    } else {
      int q = idx - 4, r = q * 16 + lrow;
      int col = ((c4 ^ ((r >> 1) & 3)) << 3);
      src[i] = bp + (size_t)r * II + col;
      dst[i] = Bs + q * 512;
    }
  }
  int offA[2], offB[4];
  #pragma unroll
  for (int mi = 0; mi < 2; mi++) {
    int r = wm + mi * 16 + l16;
    offA[mi] = r * 32 + ((quad ^ ((r >> 1) & 3)) << 3);
  }
  #pragma unroll
  for (int ni = 0; ni < 4; ni++) {
    int r = wn + ni * 16 + l16;
    offB[ni] = r * 32 + ((quad ^ ((r >> 1) & 3)) << 3);
  }

  for (int k0 = 0; k0 < II; k0 += 32) {
    if (k0) __syncthreads();
    #pragma unroll
    for (int i = 0; i < 3; i++) { async_copy16(src[i], dst[i]); src[i] += 32; }
    __syncthreads();

    bf16x8 af0 = *(const bf16x8*)(As + offA[0]);
    bf16x8 af1 = *(const bf16x8*)(As + offA[1]);
    #pragma unroll
    for (int ni = 0; ni < 4; ni++) {
      bf16x8 bf_ = *(const bf16x8*)(Bs + offB[ni]);
      acc[0][ni] = __builtin_amdgcn_mfma_f32_16x16x32_bf16(af0, bf_, acc[0][ni], 0, 0, 0);
      acc[1][ni] = __builtin_amdgcn_mfma_f32_16x16x32_bf16(af1, bf_, acc[1][ni], 0, 0, 0);
    }
  }

  #pragma unroll
  for (int mi = 0; mi < 2; mi++)
    #pragma unroll
    for (int ni = 0; ni < 4; ni++) {
      #pragma unroll
      for (int r = 0; r < 4; r++) {
        int row = wm + mi * 16 + quad * 4 + r;
        int p = m0 + row;
        if (p < M) {
          float val = acc[mi][ni][r] * sGw[row];
          atomicAdd(out + (size_t)sTok[row] * HH + (n0 + wn + ni * 16 + l16), val);
        }
      }
    }
}

// ---------------- host ----------------
extern "C" void kernel_launch(void* const* d_in, const int* in_sizes, int n_in,
                              void* d_out, int out_size, void* d_ws, size_t ws_size,
                              hipStream_t stream)
{
  const float* x  = (const float*)d_in[0];
  const float* Wr = (const float*)d_in[1];
  const float* Wg = (const float*)d_in[2];
  const float* Wu = (const float*)d_in[3];
  const float* Wd = (const float*)d_in[4];
  float* out = (float*)d_out;
  char* ws = (char*)d_ws;

  // workspace layout (bytes): total ~75.9 MB
  int*    cnt      = (int*)(ws + 0);          // 8 ints (zeroed)
  int*    offs     = (int*)(ws + 256);        // 8 ints
  float*  impPart  = (float*)(ws + 512);      // 1024*8 floats (32 KB)
  int*    pair     = (int*)(ws + 33280);      // T ints (16 KB)
  float2* w2       = (float2*)(ws + 49664);   // T float2 (32 KB)
  int*    tok_list = (int*)(ws + 98304);      // E*T ints   (128 KB)
  float*  gate_ls  = (float*)(ws + 229376);   // E*T floats (128 KB)
  bf16*   xb       = (bf16*)(ws + 360448);    // T*H bf16   (8 MB)
  bf16*   wgb      = (bf16*)(ws + 8749056);   // E*I*H bf16 (16 MB, transposed [e][i][h])
  bf16*   wub      = (bf16*)(ws + 25526272);  // 16 MB
  bf16*   wdb      = (bf16*)(ws + 42303488);  // 16 MB, transposed [e][h][i]
  bf16*   inter    = (bf16*)(ws + 59080704);  // 2T*I bf16  (16 MB, compact slots)

  hipMemsetAsync(ws, 0, 512, stream);                                   // cnt
  hipMemsetAsync(d_out, 0, (size_t)out_size * sizeof(float), stream);   // atomic accum base

  transpose_convert3<<<dim3(32, 32, 24), dim3(32, 8), 0, stream>>>(Wg, Wu, Wd, wgb, wub, wdb);
  router_kernel<<<1024, 256, 0, stream>>>(x, Wr, xb, pair, w2, impPart);
  scatter_kernel<<<16, 256, 0, stream>>>(pair, w2, cnt, tok_list, gate_ls);
  finalize_kernel<<<1, 256, 0, stream>>>(cnt, impPart, offs, out + (size_t)TT * HH);
  gemm1_kernel<<<dim3(8, 64, 8), 256, 0, stream>>>(xb, wgb, wub, cnt, offs, tok_list, inter);
  gemm2_kernel<<<dim3(8, 64, 8), 256, 0, stream>>>(inter, wdb, cnt, offs, tok_list, gate_ls, out);
}

// Round 5
// 292.535 us; speedup vs baseline: 2.5480x; 1.0765x over previous
//
#include <hip/hip_runtime.h>
#include <hip/hip_bf16.h>
#include <math.h>

#define TT 4096   // tokens (B*S)
#define HH 1024   // hidden
#define EE 8      // experts
#define II 1024   // intermediate

typedef __bf16 bf16x8 __attribute__((ext_vector_type(8)));
typedef float  floatx4 __attribute__((ext_vector_type(4)));
typedef __hip_bfloat16 bf16;

// async global->LDS, 16B per lane. LDS dest is wave-uniform base + lane*16;
// global address is per-lane (gather allowed).
__device__ __forceinline__ void async_copy16(const void* g, void* s) {
  __builtin_amdgcn_global_load_lds((__attribute__((address_space(1))) void*)g,
                                   (__attribute__((address_space(3))) void*)s,
                                   16, 0, 0);
}

// Rows are 64 elems (128 B) in LDS = 8 chunks of 16 B.
// XOR swizzle: logical chunk lc of row r lives at phys chunk lc ^ (r&7).
// b128 reads then hit all 32 banks at most 2-way (free, m136).

// ---------------- weight transpose+convert (all 3 weights in one launch) ----------------
// R3-verified scalar store (R4's bf162 store read tile[] out of bounds — absmax 1768).
__global__ __launch_bounds__(256) void transpose_convert3(
    const float* __restrict__ Wg, const float* __restrict__ Wu, const float* __restrict__ Wd,
    bf16* __restrict__ wgb, bf16* __restrict__ wub, bf16* __restrict__ wdb) {
  __shared__ float tile[32][33];
  const int zi = blockIdx.z >> 3, e = blockIdx.z & 7;
  const float* s = (zi == 0 ? Wg : zi == 1 ? Wu : Wd) + (size_t)e * 1024 * 1024;
  bf16* d = (zi == 0 ? wgb : zi == 1 ? wub : wdb) + (size_t)e * 1024 * 1024;
  const int tx = threadIdx.x, ty = threadIdx.y;     // 32 x 8
  const int r0 = blockIdx.y * 32, c0 = blockIdx.x * 32;
  #pragma unroll
  for (int i = 0; i < 32; i += 8)
    tile[ty + i][tx] = s[(size_t)(r0 + ty + i) * 1024 + (c0 + tx)];
  __syncthreads();
  #pragma unroll
  for (int i = 0; i < 32; i += 8)
    d[(size_t)(c0 + ty + i) * 1024 + (r0 + tx)] = __float2bfloat16(tile[tx][ty + i]);
}

// ---------------- router: logits, top-2 -> per-token records; per-block imp partials; x->bf16 ----------------
__global__ __launch_bounds__(256) void router_kernel(
    const float* __restrict__ x, const float* __restrict__ Wr,
    bf16* __restrict__ xb, int* __restrict__ pair, float2* __restrict__ w2,
    float* __restrict__ impPart)
{
  __shared__ float simp[8];
  const int tid = threadIdx.x;
  if (tid < 8) simp[tid] = 0.f;
  __syncthreads();

  const int w = tid >> 6, lane = tid & 63;
  const int t = blockIdx.x * 4 + w;
  const float* xr = x + (size_t)t * HH;
  float acc[8] = {0.f,0.f,0.f,0.f,0.f,0.f,0.f,0.f};
  #pragma unroll
  for (int i = 0; i < 16; i++) {
    int h = lane + i * 64;
    float xv = xr[h];
    xb[(size_t)t * HH + h] = __float2bfloat16(xv);
    const float4* wr = (const float4*)(Wr + h * 8);
    float4 a = wr[0], b = wr[1];
    acc[0] += xv * a.x; acc[1] += xv * a.y; acc[2] += xv * a.z; acc[3] += xv * a.w;
    acc[4] += xv * b.x; acc[5] += xv * b.y; acc[6] += xv * b.z; acc[7] += xv * b.w;
  }
  #pragma unroll
  for (int e = 0; e < 8; e++) {
    #pragma unroll
    for (int off = 32; off > 0; off >>= 1)
      acc[e] += __shfl_xor(acc[e], off);
  }
  if (lane == 0) {
    int i0 = 0;
    #pragma unroll
    for (int e = 1; e < 8; e++) if (acc[e] > acc[i0]) i0 = e;   // lowest index wins ties, like lax.top_k
    int i1 = (i0 == 0) ? 1 : 0;
    #pragma unroll
    for (int e = 0; e < 8; e++) if (e != i0 && acc[e] > acc[i1]) i1 = e;
    float mx = acc[i0];
    float pe[8]; float s = 0.f;
    #pragma unroll
    for (int e = 0; e < 8; e++) { pe[e] = __expf(acc[e] - mx); s += pe[e]; }
    float inv = 1.f / s;
    #pragma unroll
    for (int e = 0; e < 8; e++) atomicAdd(simp + e, pe[e] * inv);   // LDS atomic: cheap
    float p0 = pe[i0] * inv, p1 = pe[i1] * inv;
    float wn2 = 1.f / (p0 + p1);
    pair[t] = i0 | (i1 << 8);
    w2[t] = make_float2(p0 * wn2, p1 * wn2);
  }
  __syncthreads();
  if (tid < 8) impPart[blockIdx.x * 8 + tid] = simp[tid];
}

// ---------------- scatter: per-block LDS histogram -> 8 global atomics/block ----------------
__global__ __launch_bounds__(256) void scatter_kernel(
    const int* __restrict__ pair, const float2* __restrict__ w2,
    int* __restrict__ cnt, int* __restrict__ tok_list, float* __restrict__ gate_ls)
{
  __shared__ int lcnt[8];
  __shared__ int lbase[8];
  const int tid = threadIdx.x;
  const int t = blockIdx.x * 256 + tid;
  if (tid < 8) lcnt[tid] = 0;
  __syncthreads();
  int pr = pair[t];
  float2 ww = w2[t];
  int e0 = pr & 0xff, e1 = pr >> 8;
  int lp0 = atomicAdd(lcnt + e0, 1);
  int lp1 = atomicAdd(lcnt + e1, 1);
  __syncthreads();
  if (tid < 8) lbase[tid] = atomicAdd(cnt + tid, lcnt[tid]);   // 8 global atomics per block
  __syncthreads();
  int p0 = lbase[e0] + lp0, p1 = lbase[e1] + lp1;
  tok_list[e0 * TT + p0] = t; gate_ls[e0 * TT + p0] = ww.x;
  tok_list[e1 * TT + p1] = t; gate_ls[e1 * TT + p1] = ww.y;
}

// ---------------- finalize: reduce imp partials, prefix offsets, aux loss ----------------
__global__ __launch_bounds__(256) void finalize_kernel(
    const int* __restrict__ cnt, const float* __restrict__ impPart,
    int* __restrict__ offs, float* __restrict__ aux_out)
{
  __shared__ float part[256];
  __shared__ float impf[8];
  const int tid = threadIdx.x;
  const int e = tid & 7, r = tid >> 3;          // 32 chunks x 8 experts
  float s = 0.f;
  for (int i = r; i < 1024; i += 32) s += impPart[i * 8 + e];
  part[tid] = s;
  __syncthreads();
  if (tid < 8) {
    float ss = 0.f;
    #pragma unroll
    for (int j = 0; j < 32; j++) ss += part[j * 8 + tid];
    impf[tid] = ss;
  }
  __syncthreads();
  if (tid == 0) {
    int o = 0; float sl = 0.f;
    for (int e2 = 0; e2 < 8; e2++) { offs[e2] = o; o += cnt[e2]; sl += (float)cnt[e2] * impf[e2]; }
    aux_out[0] = (float)EE * 0.01f * sl / ((float)TT * (float)TT);
  }
}

// ---------------- gemm1: inter = silu(A@Wg) * (A@Wu); 128x128 tile, BK=64, 64x64/wave ----------------
__global__ __launch_bounds__(256, 2) void gemm1_kernel(
    const bf16* __restrict__ xb, const bf16* __restrict__ wg, const bf16* __restrict__ wu,
    const int* __restrict__ cnt, const int* __restrict__ offs,
    const int* __restrict__ tok_list, bf16* __restrict__ inter)
{
  const int e = blockIdx.z;
  const int M = cnt[e];
  const int m0 = blockIdx.y * 128;
  if (m0 >= M) return;
  const int n0 = blockIdx.x * 128;
  const int off = offs[e];

  __shared__ alignas(16) bf16 As[128 * 64];   // 16 KB, 16 chunks of 1KB
  __shared__ alignas(16) bf16 Bg[128 * 64];   // 16 KB
  __shared__ alignas(16) bf16 Bu[128 * 64];   // 16 KB
  __shared__ int sTok[128];

  const int tid = threadIdx.x;
  if (tid < 128) {
    int p = m0 + tid;
    sTok[tid] = tok_list[e * TT + (p < M ? p : M - 1)];
  }

  const int w = tid >> 6, lane = tid & 63;
  const int quad = lane >> 4, l16 = lane & 15;
  const int srow = lane >> 3, schunk = lane & 7;   // staging: 8 rows x 8 chunks per issue
  const int wm = (w >> 1) * 64, wn = (w & 1) * 64;

  const bf16* bgp = wg + ((size_t)e * II + n0) * HH;  // [n][k] rows
  const bf16* bup = wu + ((size_t)e * II + n0) * HH;

  floatx4 zero4 = {0.f, 0.f, 0.f, 0.f};
  floatx4 accg[4][4], accu[4][4];
  #pragma unroll
  for (int mi = 0; mi < 4; mi++)
    #pragma unroll
    for (int ni = 0; ni < 4; ni++) { accg[mi][ni] = zero4; accu[mi][ni] = zero4; }

  __syncthreads();  // sTok visible

  // 48 staging issues (16 A + 16 Bg + 16 Bu), 12 per wave; k-invariant pointers
  const bf16* src[12]; bf16* dst[12];
  #pragma unroll
  for (int i = 0; i < 12; i++) {
    int idx = w + 4 * i;
    int q = idx & 15;
    int r = q * 8 + srow;
    int col = ((schunk ^ (r & 7)) << 3);
    if (idx < 16) {
      src[i] = xb + (size_t)sTok[r] * HH + col;
      dst[i] = As + q * 512;
    } else if (idx < 32) {
      src[i] = bgp + (size_t)r * HH + col;
      dst[i] = Bg + q * 512;
    } else {
      src[i] = bup + (size_t)r * HH + col;
      dst[i] = Bu + q * 512;
    }
  }
  // k-invariant swizzled LDS read offsets: [mi/ni][half]
  int offA[4][2], offB[4][2];
  #pragma unroll
  for (int mi = 0; mi < 4; mi++) {
    int r = wm + mi * 16 + l16;
    #pragma unroll
    for (int h = 0; h < 2; h++)
      offA[mi][h] = r * 64 + (((h * 4 + quad) ^ (r & 7)) << 3);
  }
  #pragma unroll
  for (int ni = 0; ni < 4; ni++) {
    int r = wn + ni * 16 + l16;
    #pragma unroll
    for (int h = 0; h < 2; h++)
      offB[ni][h] = r * 64 + (((h * 4 + quad) ^ (r & 7)) << 3);
  }

  for (int k0 = 0; k0 < HH; k0 += 64) {
    if (k0) __syncthreads();                 // prior compute done before LDS overwrite
    #pragma unroll
    for (int i = 0; i < 12; i++) { async_copy16(src[i], dst[i]); src[i] += 64; }
    __syncthreads();                         // vmcnt drained by barrier semantics

    bf16x8 af[4][2];
    #pragma unroll
    for (int mi = 0; mi < 4; mi++) {
      af[mi][0] = *(const bf16x8*)(As + offA[mi][0]);
      af[mi][1] = *(const bf16x8*)(As + offA[mi][1]);
    }
    #pragma unroll
    for (int ni = 0; ni < 4; ni++) {
      bf16x8 bg0 = *(const bf16x8*)(Bg + offB[ni][0]);
      bf16x8 bg1 = *(const bf16x8*)(Bg + offB[ni][1]);
      bf16x8 bu0 = *(const bf16x8*)(Bu + offB[ni][0]);
      bf16x8 bu1 = *(const bf16x8*)(Bu + offB[ni][1]);
      #pragma unroll
      for (int mi = 0; mi < 4; mi++) {
        accg[mi][ni] = __builtin_amdgcn_mfma_f32_16x16x32_bf16(af[mi][0], bg0, accg[mi][ni], 0, 0, 0);
        accg[mi][ni] = __builtin_amdgcn_mfma_f32_16x16x32_bf16(af[mi][1], bg1, accg[mi][ni], 0, 0, 0);
        accu[mi][ni] = __builtin_amdgcn_mfma_f32_16x16x32_bf16(af[mi][0], bu0, accu[mi][ni], 0, 0, 0);
        accu[mi][ni] = __builtin_amdgcn_mfma_f32_16x16x32_bf16(af[mi][1], bu1, accu[mi][ni], 0, 0, 0);
      }
    }
  }

  // epilogue: silu(g)*u -> bf16 inter (compact slots), C/D: row=quad*4+reg, col=lane&15
  #pragma unroll
  for (int mi = 0; mi < 4; mi++)
    #pragma unroll
    for (int ni = 0; ni < 4; ni++) {
      #pragma unroll
      for (int r = 0; r < 4; r++) {
        int row = wm + mi * 16 + quad * 4 + r;
        int p = m0 + row;
        if (p < M) {
          float gv = accg[mi][ni][r], uv = accu[mi][ni][r];
          float val = gv / (1.f + __expf(-gv)) * uv;
          inter[(size_t)(off + p) * II + (n0 + wn + ni * 16 + l16)] = __float2bfloat16(val);
        }
      }
    }
}

// ---------------- gemm2: out += gate * (inter @ Wd^T); 128x128 tile, BK=64 ----------------
__global__ __launch_bounds__(256, 2) void gemm2_kernel(
    const bf16* __restrict__ inter, const bf16* __restrict__ wd,
    const int* __restrict__ cnt, const int* __restrict__ offs,
    const int* __restrict__ tok_list, const float* __restrict__ gate_ls,
    float* __restrict__ out)
{
  const int e = blockIdx.z;
  const int M = cnt[e];
  const int m0 = blockIdx.y * 128;
  if (m0 >= M) return;
  const int n0 = blockIdx.x * 128;
  const int off = offs[e];

  __shared__ alignas(16) bf16 As[128 * 64];   // 16 KB
  __shared__ alignas(16) bf16 Bs[128 * 64];   // 16 KB
  __shared__ int sTok[128];
  __shared__ float sGw[128];

  const int tid = threadIdx.x;
  if (tid < 128) {
    int p = m0 + tid;
    int pc = p < M ? p : M - 1;
    sTok[tid] = tok_list[e * TT + pc];
    sGw[tid]  = gate_ls[e * TT + pc];
  }
  const int w = tid >> 6, lane = tid & 63;
  const int quad = lane >> 4, l16 = lane & 15;
  const int srow = lane >> 3, schunk = lane & 7;
  const int wm = (w >> 1) * 64, wn = (w & 1) * 64;
  const bf16* bp = wd + ((size_t)e * HH + n0) * II;   // [n=h][k=i] rows

  floatx4 zero4 = {0.f, 0.f, 0.f, 0.f};
  floatx4 acc[4][4];
  #pragma unroll
  for (int mi = 0; mi < 4; mi++)
    #pragma unroll
    for (int ni = 0; ni < 4; ni++) acc[mi][ni] = zero4;

  __syncthreads();

  // 32 staging issues (16 A + 16 B), 8 per wave
  const bf16* src[8]; bf16* dst[8];
  #pragma unroll
  for (int i = 0; i < 8; i++) {
    int idx = w + 4 * i;
    int q = idx & 15;
    int r = q * 8 + srow;
    int col = ((schunk ^ (r & 7)) << 3);
    if (idx < 16) {
      int p = m0 + r; int pc = p < M ? p : M - 1;
      src[i] = inter + (size_t)(off + pc) * II + col;
      dst[i] = As + q * 512;
    } else {
      src[i] = bp + (size_t)r * II + col;
      dst[i] = Bs + q * 512;
    }
  }
  int offA[4][2], offB[4][2];
  #pragma unroll
  for (int mi = 0; mi < 4; mi++) {
    int r = wm + mi * 16 + l16;
    #pragma unroll
    for (int h = 0; h < 2; h++)
      offA[mi][h] = r * 64 + (((h * 4 + quad) ^ (r & 7)) << 3);
  }
  #pragma unroll
  for (int ni = 0; ni < 4; ni++) {
    int r = wn + ni * 16 + l16;
    #pragma unroll
    for (int h = 0; h < 2; h++)
      offB[ni][h] = r * 64 + (((h * 4 + quad) ^ (r & 7)) << 3);
  }

  for (int k0 = 0; k0 < II; k0 += 64) {
    if (k0) __syncthreads();
    #pragma unroll
    for (int i = 0; i < 8; i++) { async_copy16(src[i], dst[i]); src[i] += 64; }
    __syncthreads();

    bf16x8 af[4][2];
    #pragma unroll
    for (int mi = 0; mi < 4; mi++) {
      af[mi][0] = *(const bf16x8*)(As + offA[mi][0]);
      af[mi][1] = *(const bf16x8*)(As + offA[mi][1]);
    }
    #pragma unroll
    for (int ni = 0; ni < 4; ni++) {
      bf16x8 b0 = *(const bf16x8*)(Bs + offB[ni][0]);
      bf16x8 b1 = *(const bf16x8*)(Bs + offB[ni][1]);
      #pragma unroll
      for (int mi = 0; mi < 4; mi++) {
        acc[mi][ni] = __builtin_amdgcn_mfma_f32_16x16x32_bf16(af[mi][0], b0, acc[mi][ni], 0, 0, 0);
        acc[mi][ni] = __builtin_amdgcn_mfma_f32_16x16x32_bf16(af[mi][1], b1, acc[mi][ni], 0, 0, 0);
      }
    }
  }

  #pragma unroll
  for (int mi = 0; mi < 4; mi++)
    #pragma unroll
    for (int ni = 0; ni < 4; ni++) {
      #pragma unroll
      for (int r = 0; r < 4; r++) {
        int row = wm + mi * 16 + quad * 4 + r;
        int p = m0 + row;
        if (p < M) {
          float val = acc[mi][ni][r] * sGw[row];
          atomicAdd(out + (size_t)sTok[row] * HH + (n0 + wn + ni * 16 + l16), val);
        }
      }
    }
}

// ---------------- host ----------------
extern "C" void kernel_launch(void* const* d_in, const int* in_sizes, int n_in,
                              void* d_out, int out_size, void* d_ws, size_t ws_size,
                              hipStream_t stream)
{
  const float* x  = (const float*)d_in[0];
  const float* Wr = (const float*)d_in[1];
  const float* Wg = (const float*)d_in[2];
  const float* Wu = (const float*)d_in[3];
  const float* Wd = (const float*)d_in[4];
  float* out = (float*)d_out;
  char* ws = (char*)d_ws;

  // workspace layout (bytes): total ~75.9 MB
  int*    cnt      = (int*)(ws + 0);          // 8 ints (zeroed)
  int*    offs     = (int*)(ws + 256);        // 8 ints
  float*  impPart  = (float*)(ws + 512);      // 1024*8 floats (32 KB)
  int*    pair     = (int*)(ws + 33280);      // T ints (16 KB)
  float2* w2       = (float2*)(ws + 49664);   // T float2 (32 KB)
  int*    tok_list = (int*)(ws + 98304);      // E*T ints   (128 KB)
  float*  gate_ls  = (float*)(ws + 229376);   // E*T floats (128 KB)
  bf16*   xb       = (bf16*)(ws + 360448);    // T*H bf16   (8 MB)
  bf16*   wgb      = (bf16*)(ws + 8749056);   // E*I*H bf16 (16 MB, transposed [e][i][h])
  bf16*   wub      = (bf16*)(ws + 25526272);  // 16 MB
  bf16*   wdb      = (bf16*)(ws + 42303488);  // 16 MB, transposed [e][h][i]
  bf16*   inter    = (bf16*)(ws + 59080704);  // 2T*I bf16  (16 MB, compact slots)

  hipMemsetAsync(ws, 0, 512, stream);                                   // cnt
  hipMemsetAsync(d_out, 0, (size_t)out_size * sizeof(float), stream);   // atomic accum base

  transpose_convert3<<<dim3(32, 32, 24), dim3(32, 8), 0, stream>>>(Wg, Wu, Wd, wgb, wub, wdb);
  router_kernel<<<1024, 256, 0, stream>>>(x, Wr, xb, pair, w2, impPart);
  scatter_kernel<<<16, 256, 0, stream>>>(pair, w2, cnt, tok_list, gate_ls);
  finalize_kernel<<<1, 256, 0, stream>>>(cnt, impPart, offs, out + (size_t)TT * HH);
  gemm1_kernel<<<dim3(8, 32, 8), 256, 0, stream>>>(xb, wgb, wub, cnt, offs, tok_list, inter);
  gemm2_kernel<<<dim3(8, 32, 8), 256, 0, stream>>>(inter, wdb, cnt, offs, tok_list, gate_ls, out);
}